// Round 1
// baseline (98.860 us; speedup 1.0000x reference)
//
#include <hip/hip_runtime.h>

// ContrastiveLoss cosine: B=4096 rows, D=1024, fp32.
// out layout: [0]=loss, [1..B]=i2t_cosine, [1+B..2B]=t2i_cosine (identical values).
// ws layout (floats): n_img[B], n_txt[B], pos_dist[B], trip[B].

constexpr int B = 4096;
constexpr int D = 1024;
#define EPSF 1e-8f
#define MARGIN 0.2f

__device__ __forceinline__ float waveReduceSum(float v) {
#pragma unroll
    for (int off = 32; off > 0; off >>= 1)
        v += __shfl_xor(v, off, 64);
    return v;
}

__device__ __forceinline__ float dot4(float4 a, float4 b) {
    return a.x * b.x + a.y * b.y + a.z * b.z + a.w * b.w;
}

// Kernel 1: per-row dot(img,txt), norms, pos_dist, cosine outputs.
// One wave (64 lanes) per row; 4 waves per 256-thread block.
__global__ __launch_bounds__(256) void k1_rows(
    const float* __restrict__ img, const float* __restrict__ txt,
    float* __restrict__ n1, float* __restrict__ n2,
    float* __restrict__ posd, float* __restrict__ out) {
    const int wave = threadIdx.x >> 6;
    const int lane = threadIdx.x & 63;
    const int row = blockIdx.x * 4 + wave;
    if (row >= B) return;

    const float4* __restrict__ ir = (const float4*)(img + (size_t)row * D);
    const float4* __restrict__ tr = (const float4*)(txt + (size_t)row * D);

    float sd = 0.f, s1 = 0.f, s2 = 0.f;
#pragma unroll
    for (int j = 0; j < 4; ++j) {
        const int idx = j * 64 + lane;           // 256 float4 per row
        float4 a = ir[idx];
        float4 b = tr[idx];
        sd += dot4(a, b);
        s1 += dot4(a, a);
        s2 += dot4(b, b);
    }
    sd = waveReduceSum(sd);
    s1 = waveReduceSum(s1);
    s2 = waveReduceSum(s2);

    if (lane == 0) {
        const float na = sqrtf(s1);
        const float nb = sqrtf(s2);
        n1[row] = na;
        n2[row] = nb;
        const float prod = na * nb;
        const float cosv = sd / prod;                     // unclamped (sim)
        posd[row] = 1.0f - sd / fmaxf(prod, EPSF);        // clamped (dist)
        out[1 + row] = cosv;          // i2t_cosine
        out[1 + B + row] = cosv;      // t2i_cosine (identical by construction)
    }
}

// Kernel 2: candidate dots, hard-negative selection, triplet per row.
__global__ __launch_bounds__(256) void k2_neg(
    const float* __restrict__ img, const float* __restrict__ txt,
    const int* __restrict__ ci, const int* __restrict__ ct,
    const float* __restrict__ n1, const float* __restrict__ n2,
    const float* __restrict__ posd, float* __restrict__ trip) {
    const int wave = threadIdx.x >> 6;
    const int lane = threadIdx.x & 63;
    const int row = blockIdx.x * 4 + wave;
    if (row >= B) return;

    const int c0 = ci[row * 2 + 0];   // img-candidate ids (anchor = txt row)
    const int c1 = ci[row * 2 + 1];
    const int e0 = ct[row * 2 + 0];   // txt-candidate ids (anchor = img row)
    const int e1 = ct[row * 2 + 1];

    const float4* __restrict__ tb = (const float4*)(txt + (size_t)row * D);
    const float4* __restrict__ ib = (const float4*)(img + (size_t)row * D);
    const float4* __restrict__ i0 = (const float4*)(img + (size_t)c0 * D);
    const float4* __restrict__ i1 = (const float4*)(img + (size_t)c1 * D);
    const float4* __restrict__ t0 = (const float4*)(txt + (size_t)e0 * D);
    const float4* __restrict__ t1 = (const float4*)(txt + (size_t)e1 * D);

    float a0 = 0.f, a1 = 0.f, a2 = 0.f, a3 = 0.f;
#pragma unroll
    for (int j = 0; j < 4; ++j) {
        const int idx = j * 64 + lane;
        float4 t = tb[idx];
        float4 x0 = i0[idx];
        float4 x1 = i1[idx];
        a0 += dot4(t, x0);
        a1 += dot4(t, x1);
        float4 u = ib[idx];
        float4 y0 = t0[idx];
        float4 y1 = t1[idx];
        a2 += dot4(u, y0);
        a3 += dot4(u, y1);
    }
    a0 = waveReduceSum(a0);
    a1 = waveReduceSum(a1);
    a2 = waveReduceSum(a2);
    a3 = waveReduceSum(a3);

    if (lane == 0) {
        const float nib = n1[row];   // ||img[row]||
        const float ntb = n2[row];   // ||txt[row]||
        // t2i negative: anchor txt[row] vs img candidates
        const float d0 = 1.f - a0 / fmaxf(ntb * n1[c0], EPSF);
        const float d1 = 1.f - a1 / fmaxf(ntb * n1[c1], EPSF);
        const float t2i_neg = (d1 <= d0) ? d1 : d0;  // '<=': later candidate wins ties
        // i2t negative: anchor img[row] vs txt candidates
        const float g0 = 1.f - a2 / fmaxf(nib * n2[e0], EPSF);
        const float g1 = 1.f - a3 / fmaxf(nib * n2[e1], EPSF);
        const float i2t_neg = (g1 <= g0) ? g1 : g0;

        const float pos = posd[row];
        const float i2t = fmaxf(pos - i2t_neg + MARGIN, 0.f);
        const float t2i = fmaxf(pos - t2i_neg + MARGIN, 0.f);
        trip[row] = i2t + t2i;
    }
}

// Kernel 3: deterministic reduction of trip[B] -> loss = sum / B.
__global__ __launch_bounds__(1024) void k3_reduce(
    const float* __restrict__ trip, float* __restrict__ out) {
    __shared__ float s[1024];
    const int t = threadIdx.x;
    float v = trip[t] + trip[t + 1024] + trip[t + 2048] + trip[t + 3072];
    s[t] = v;
    __syncthreads();
#pragma unroll
    for (int off = 512; off >= 64; off >>= 1) {
        if (t < off) s[t] += s[t + off];
        __syncthreads();
    }
    if (t < 64) {
        float x = s[t];
        x = waveReduceSum(x);
        if (t == 0) out[0] = x * (1.0f / (float)B);
    }
}

extern "C" void kernel_launch(void* const* d_in, const int* in_sizes, int n_in,
                              void* d_out, int out_size, void* d_ws, size_t ws_size,
                              hipStream_t stream) {
    const float* img = (const float*)d_in[0];
    const float* txt = (const float*)d_in[1];
    // d_in[2]=labels (unused), d_in[3]=locations (unused)
    const int* ci = (const int*)d_in[4];
    const int* ct = (const int*)d_in[5];
    float* out = (float*)d_out;

    float* ws = (float*)d_ws;
    float* n1 = ws;            // ||img[b]||
    float* n2 = ws + B;        // ||txt[b]||
    float* posd = ws + 2 * B;  // pos_dist[b]
    float* trip = ws + 3 * B;  // per-row triplet sum

    k1_rows<<<B / 4, 256, 0, stream>>>(img, txt, n1, n2, posd, out);
    k2_neg<<<B / 4, 256, 0, stream>>>(img, txt, ci, ct, n1, n2, posd, trip);
    k3_reduce<<<1, 1024, 0, stream>>>(trip, out);
}

// Round 2
// 93.434 us; speedup vs baseline: 1.0581x; 1.0581x over previous
//
#include <hip/hip_runtime.h>

// ContrastiveLoss cosine: B=4096 rows, D=1024, fp32.
// out layout: [0]=loss, [1..B]=i2t_cosine, [1+B..2B]=t2i_cosine (identical values).
// ws layout (floats): trip[B].
//
// Single fused row kernel: candidate norms are computed in the same pass as the
// candidate dots (the row is already being read), so no separate norm pass and
// no inter-kernel dependency. Then one deterministic tree-reduce kernel.

constexpr int B = 4096;
constexpr int D = 1024;
#define EPSF 1e-8f
#define MARGIN 0.2f

__device__ __forceinline__ float waveReduceSum(float v) {
#pragma unroll
    for (int off = 32; off > 0; off >>= 1)
        v += __shfl_xor(v, off, 64);
    return v;
}

__device__ __forceinline__ float dot4(float4 a, float4 b) {
    return a.x * b.x + a.y * b.y + a.z * b.z + a.w * b.w;
}

// One wave (64 lanes) per row; 4 waves per 256-thread block.
// Per row, 11 dot-products over D=1024 in a single read pass of 6 rows:
//   sd = img.txt          s1 = |img|^2        s2 = |txt|^2
//   a0/a1 = txt.img[c]    q0/q1 = |img[c]|^2   (t2i negatives)
//   a2/a3 = img.txt[e]    r0/r1 = |txt[e]|^2   (i2t negatives)
__global__ __launch_bounds__(256) void fused_rows(
    const float* __restrict__ img, const float* __restrict__ txt,
    const int* __restrict__ ci, const int* __restrict__ ct,
    float* __restrict__ out, float* __restrict__ trip) {
    const int wave = threadIdx.x >> 6;
    const int lane = threadIdx.x & 63;
    const int row = blockIdx.x * 4 + wave;

    const int c0 = ci[row * 2 + 0];
    const int c1 = ci[row * 2 + 1];
    const int e0 = ct[row * 2 + 0];
    const int e1 = ct[row * 2 + 1];

    const float4* __restrict__ ib = (const float4*)(img + (size_t)row * D);
    const float4* __restrict__ tb = (const float4*)(txt + (size_t)row * D);
    const float4* __restrict__ i0 = (const float4*)(img + (size_t)c0 * D);
    const float4* __restrict__ i1 = (const float4*)(img + (size_t)c1 * D);
    const float4* __restrict__ t0 = (const float4*)(txt + (size_t)e0 * D);
    const float4* __restrict__ t1 = (const float4*)(txt + (size_t)e1 * D);

    float sd = 0.f, s1 = 0.f, s2 = 0.f;
    float a0 = 0.f, a1 = 0.f, a2 = 0.f, a3 = 0.f;
    float q0 = 0.f, q1 = 0.f, r0 = 0.f, r1 = 0.f;
#pragma unroll
    for (int j = 0; j < 4; ++j) {
        const int idx = j * 64 + lane;  // 256 float4 per row
        float4 A = ib[idx];
        float4 T = tb[idx];
        float4 X0 = i0[idx];
        float4 X1 = i1[idx];
        float4 Y0 = t0[idx];
        float4 Y1 = t1[idx];
        sd += dot4(A, T);
        s1 += dot4(A, A);
        s2 += dot4(T, T);
        a0 += dot4(T, X0);
        q0 += dot4(X0, X0);
        a1 += dot4(T, X1);
        q1 += dot4(X1, X1);
        a2 += dot4(A, Y0);
        r0 += dot4(Y0, Y0);
        a3 += dot4(A, Y1);
        r1 += dot4(Y1, Y1);
    }
    sd = waveReduceSum(sd);
    s1 = waveReduceSum(s1);
    s2 = waveReduceSum(s2);
    a0 = waveReduceSum(a0);
    a1 = waveReduceSum(a1);
    a2 = waveReduceSum(a2);
    a3 = waveReduceSum(a3);
    q0 = waveReduceSum(q0);
    q1 = waveReduceSum(q1);
    r0 = waveReduceSum(r0);
    r1 = waveReduceSum(r1);

    if (lane == 0) {
        const float na = sqrtf(s1);   // ||img[row]||
        const float nb = sqrtf(s2);   // ||txt[row]||
        const float prod = na * nb;
        const float cosv = sd / prod;                  // unclamped (sim)
        const float pos = 1.f - sd / fmaxf(prod, EPSF);  // clamped (dist)
        // t2i negative: anchor txt[row] vs img candidates
        const float d0 = 1.f - a0 / fmaxf(nb * sqrtf(q0), EPSF);
        const float d1 = 1.f - a1 / fmaxf(nb * sqrtf(q1), EPSF);
        const float t2i_neg = (d1 <= d0) ? d1 : d0;  // '<=': later wins ties
        // i2t negative: anchor img[row] vs txt candidates
        const float g0 = 1.f - a2 / fmaxf(na * sqrtf(r0), EPSF);
        const float g1 = 1.f - a3 / fmaxf(na * sqrtf(r1), EPSF);
        const float i2t_neg = (g1 <= g0) ? g1 : g0;

        out[1 + row] = cosv;          // i2t_cosine
        out[1 + B + row] = cosv;      // t2i_cosine (identical by construction)
        trip[row] = fmaxf(pos - i2t_neg + MARGIN, 0.f)
                  + fmaxf(pos - t2i_neg + MARGIN, 0.f);
    }
}

// Deterministic reduction of trip[B] -> loss = sum / B.
__global__ __launch_bounds__(1024) void k_reduce(
    const float* __restrict__ trip, float* __restrict__ out) {
    __shared__ float s[1024];
    const int t = threadIdx.x;
    float v = trip[t] + trip[t + 1024] + trip[t + 2048] + trip[t + 3072];
    s[t] = v;
    __syncthreads();
#pragma unroll
    for (int off = 512; off >= 64; off >>= 1) {
        if (t < off) s[t] += s[t + off];
        __syncthreads();
    }
    if (t < 64) {
        float x = s[t];
        x = waveReduceSum(x);
        if (t == 0) out[0] = x * (1.0f / (float)B);
    }
}

extern "C" void kernel_launch(void* const* d_in, const int* in_sizes, int n_in,
                              void* d_out, int out_size, void* d_ws, size_t ws_size,
                              hipStream_t stream) {
    const float* img = (const float*)d_in[0];
    const float* txt = (const float*)d_in[1];
    // d_in[2]=labels (unused), d_in[3]=locations (unused)
    const int* ci = (const int*)d_in[4];
    const int* ct = (const int*)d_in[5];
    float* out = (float*)d_out;
    float* trip = (float*)d_ws;

    fused_rows<<<B / 4, 256, 0, stream>>>(img, txt, ci, ct, out, trip);
    k_reduce<<<1, 1024, 0, stream>>>(trip, out);
}